// Round 3
// baseline (128.606 us; speedup 1.0000x reference)
//
#include <hip/hip_runtime.h>

typedef __bf16 bf16x8 __attribute__((ext_vector_type(8)));
typedef float f32x4 __attribute__((ext_vector_type(4)));
typedef float f32x16 __attribute__((ext_vector_type(16)));

#define MFMA16(a,b,c) __builtin_amdgcn_mfma_f32_16x16x32_bf16(a,b,c,0,0,0)
#define MFMA32(a,b,c) __builtin_amdgcn_mfma_f32_32x32x16_bf16(a,b,c,0,0,0)

static __device__ __forceinline__ unsigned short f2bf(float f){
  union{float f;unsigned u;}v; v.f=f;
  unsigned u=v.u;
  u += 0x7fffu + ((u>>16)&1u);
  return (unsigned short)(u>>16);
}
static __device__ __forceinline__ float bf2f(unsigned short h){
  union{unsigned u;float f;}v; v.u=((unsigned)h)<<16; return v.f;
}
static __device__ __forceinline__ unsigned cvtpk(float lo, float hi){
  unsigned r;
  asm("v_cvt_pk_bf16_f32 %0, %1, %2" : "=v"(r) : "v"(lo), "v"(hi));
  return r;
}
// async global->LDS, 16B per lane. LDS dest = uniform base + lane*16 (HW).
static __device__ __forceinline__ void gload16(const void* g, void* l){
  __builtin_amdgcn_global_load_lds(
    (const __attribute__((address_space(1))) unsigned int*)(uintptr_t)g,
    (__attribute__((address_space(3))) unsigned int*)(uintptr_t)l,
    16, 0, 0);
}

#define SCALE_QK 0.08838834764831845f

// XOR swizzles (short-index): byte ^= (row&7)<<4
#define SWZ128(r,c) (((r)<<7) + ((c) ^ (((r)&7)<<3)))
#define SWZ64(r,c)  (((r)<<6) + ((c) ^ (((r)&7)<<3)))

// ---------------------------------------------------------------------------
// Kernel 1: q/k/v projections (bf16) + combined per-key bias.
//   t=0: qp = (query@q_w + q_b) * SCALE   [b][n][d]   (scale folded in!)
//   t=1: kp = key@k_w                      [b][n][d]
//   t=2: vpt = (value@v_w + v_b)^T         [b][d][n]
//        biasc[b][n] = value@vs_w + vs_b + att_bias
// ---------------------------------------------------------------------------
__global__ __launch_bounds__(256) void k_proj(
    const float* __restrict__ query, const float* __restrict__ key,
    const float* __restrict__ value, const float* __restrict__ att_bias,
    const float* __restrict__ q_w, const float* __restrict__ q_b,
    const float* __restrict__ k_w, const float* __restrict__ v_w,
    const float* __restrict__ v_b, const float* __restrict__ vs_w,
    const float* __restrict__ vs_b,
    unsigned short* __restrict__ qp, unsigned short* __restrict__ kp,
    unsigned short* __restrict__ vpt, float* __restrict__ biasc)
{
  const int t = blockIdx.y;
  const float* X = (t==0) ? query : ((t==1) ? key : value);
  const float* W = (t==0) ? q_w  : ((t==1) ? k_w : v_w);
  const int tid = threadIdx.x;
  const int row0 = blockIdx.x * 64;

  __shared__ __align__(16) unsigned short Wt[128][136];
  __shared__ __align__(16) unsigned short Xs[64][136];
  __shared__ float vsw_s[128];

  #pragma unroll 4
  for (int i=0;i<16;i++){
    int idx = tid*64 + i*4;
    float4 v4 = *(const float4*)(W + idx);
    Wt[(idx+0)&127][(idx+0)>>7] = f2bf(v4.x);
    Wt[(idx+1)&127][(idx+1)>>7] = f2bf(v4.y);
    Wt[(idx+2)&127][(idx+2)>>7] = f2bf(v4.z);
    Wt[(idx+3)&127][(idx+3)>>7] = f2bf(v4.w);
  }
  {
    const float* Xb = X + (size_t)row0*128;
    #pragma unroll
    for (int i=0;i<8;i++){
      int f4 = i*256 + tid;
      int row = f4>>5, c4 = f4&31;
      float4 v = *(const float4*)(Xb + row*128 + c4*4);
      ushort4 h;
      h.x = f2bf(v.x); h.y = f2bf(v.y); h.z = f2bf(v.z); h.w = f2bf(v.w);
      *(ushort4*)&Xs[row][c4*4] = h;
    }
  }
  if (t==2 && tid<128) vsw_s[tid] = vs_w[tid];
  __syncthreads();

  const int w = tid>>6, lane = tid&63, lr = lane&15, lg = lane>>4;
  f32x4 acc[8];
  #pragma unroll
  for (int nt=0;nt<8;nt++) acc[nt] = (f32x4){0.f,0.f,0.f,0.f};
  #pragma unroll
  for (int kk=0;kk<4;kk++){
    bf16x8 a = *(const bf16x8*)&Xs[w*16+lr][kk*32+lg*8];
    #pragma unroll
    for (int nt=0;nt<8;nt++){
      bf16x8 bb = *(const bf16x8*)&Wt[nt*16+lr][kk*32+lg*8];
      acc[nt] = MFMA16(a,bb,acc[nt]);
    }
  }
  const float* bias = (t==0) ? q_b : ((t==2) ? v_b : (const float*)nullptr);
  const float sc = (t==0) ? SCALE_QK : 1.f;
  #pragma unroll
  for (int nt=0;nt<8;nt++){
    int col = nt*16+lr;
    float bv = bias ? bias[col] : 0.f;
    #pragma unroll
    for (int r=0;r<4;r++){
      int row = row0 + w*16 + lg*4 + r;
      unsigned short h = f2bf((acc[nt][r] + bv) * sc);
      if (t==0)      qp[(size_t)row*128+col] = h;
      else if (t==1) kp[(size_t)row*128+col] = h;
      else {
        int bi = row>>12, n = row&4095;
        vpt[((size_t)bi*128+col)*4096 + n] = h;
      }
    }
  }
  if (t==2){
    int rl = tid>>2, part = tid&3;
    float s = 0.f;
    #pragma unroll
    for (int j=0;j<32;j++){
      int d = part*32+j;
      s += bf2f(Xs[rl][d]) * vsw_s[d];
    }
    s += __shfl_xor(s,1);
    s += __shfl_xor(s,2);
    if ((tid&3)==0){
      int rg = row0 + rl;
      biasc[rg] = s + vs_b[0] + att_bias[rg];
    }
  }
}

// ---------------------------------------------------------------------------
// Kernel 2: flash attention, KV-split 4-way, 32x32x16 MFMA, swapped QK^T.
//   Grid (NQ/64, 4 splits, B). Block: 64q x 1024 keys (16 tiles of 64).
//   4 waves as 2x2: wave (wr,wc) owns q in [wr*32,+32), d in [wc*64,+64).
//   Swapped QK^T: S^T = mfma(K, Q): lane holds 32 P-values for q = wr*32+(l&31)
//   at k = kt*32 + (reg&3)+8*(reg>>2)+4*(l>>5)  [measured 32x32 C layout].
//   Softmax fully in-lane + one shfl_xor(32). P->A-frags via cvt_pk + half
//   exchange (shfl_xor 32). No P LDS. Defer-max THR=8 (exact: corr==1).
//   Staging: global_load_lds w16, linear LDS dest, inverse-XOR source.
// ---------------------------------------------------------------------------
__global__ __launch_bounds__(256,4) void k_flash(
    const unsigned short* __restrict__ qp, const unsigned short* __restrict__ kp,
    const unsigned short* __restrict__ vpt, const float* __restrict__ biasc,
    unsigned short* __restrict__ opart, float* __restrict__ ml)
{
  const int b = blockIdx.z, split = blockIdx.y;
  const int q0 = blockIdx.x*64;
  const int tid = threadIdx.x;
  const int w = tid>>6, lane = tid&63;
  const int l31 = lane&31, hi = lane>>5;
  const int wr = w>>1, wc = w&1;

  __shared__ __align__(16) unsigned short Ks[64*128];   // [k][d] swizzled
  __shared__ __align__(16) unsigned short Vs[128*64];   // [d][k] swizzled
  __shared__ __align__(16) float Bs[1024];              // bias for whole split

  const unsigned short* kbase = kp  + (size_t)(b*4096 + split*1024)*128;
  const unsigned short* vbase = vpt + (size_t)b*128*4096 + split*1024;
  const float* bbase = biasc + b*4096 + split*1024;

  // prologue: bias table (linear), Q fragments (B-operand of swapped QK^T)
  gload16(bbase + w*256 + lane*4, &Bs[w*256]);
  bf16x8 qf[8];
  {
    const unsigned short* qrow = qp + ((size_t)(b*4096 + q0 + wr*32 + l31))*128;
    #pragma unroll
    for (int kk=0;kk<8;kk++) qf[kk] = *(const bf16x8*)(qrow + kk*16 + hi*8);
  }

  float m_run = -INFINITY, l_run = 0.f;
  f32x16 acc0 = {}, acc1 = {};

  for (int t=0;t<16;t++){
    const int k0 = t*64;
    __syncthreads();   // all waves done reading previous tile
    // ---- stage K (64 rows x 256B): 4 gload16 per wave, source pre-XOR'd
    {
      const char* kb = (const char*)kbase + (size_t)k0*256;
      #pragma unroll
      for (int i=0;i<4;i++){
        int row = (w*4+i)*4 + (lane>>4);
        int cb  = (lane&15)*16;
        gload16(kb + row*256 + (cb ^ ((row&7)*16)), (char*)Ks + (w*4+i)*1024);
      }
    }
    // ---- stage V^T (128 rows x 128B): 4 gload16 per wave
    {
      const char* vb = (const char*)vbase + (size_t)k0*2;
      #pragma unroll
      for (int i=0;i<4;i++){
        int row = (w*4+i)*8 + (lane>>3);
        int cb  = (lane&7)*16;
        gload16(vb + (size_t)row*8192 + (cb ^ ((row&7)*16)), (char*)Vs + (w*4+i)*1024);
      }
    }
    __syncthreads();   // drains vmcnt(0) -> tile resident

    // ---- QK^T (swapped): sc[kt] = S^T tile, k-rows kt*32.., q-cols = l31
    f32x16 sc0 = {}, sc1 = {};
    __builtin_amdgcn_s_setprio(1);
    #pragma unroll
    for (int kk=0;kk<8;kk++){
      bf16x8 a0 = *(const bf16x8*)&Ks[SWZ128(l31,      kk*16 + hi*8)];
      bf16x8 a1 = *(const bf16x8*)&Ks[SWZ128(32 + l31, kk*16 + hi*8)];
      sc0 = MFMA32(a0, qf[kk], sc0);
      sc1 = MFMA32(a1, qf[kk], sc1);
    }
    __builtin_amdgcn_s_setprio(0);

    // ---- bias add + tile max (lane's k = kt*32 + c + 8*rg + 4*hi)
    const float* Bt = &Bs[t*64];
    float tmax = -1e30f;
    #pragma unroll
    for (int rg=0; rg<4; rg++){
      float4 b0 = *(const float4*)&Bt[rg*8 + hi*4];
      float4 b1 = *(const float4*)&Bt[32 + rg*8 + hi*4];
      #pragma unroll
      for (int c=0;c<4;c++){
        sc0[rg*4+c] += ((const float*)&b0)[c];
        sc1[rg*4+c] += ((const float*)&b1)[c];
        tmax = fmaxf(tmax, fmaxf(sc0[rg*4+c], sc1[rg*4+c]));
      }
    }
    tmax = fmaxf(tmax, __shfl_xor(tmax, 32));

    // ---- defer-max: rescale only when tile max grows past THR=8 (exact)
    if (!__all(tmax <= m_run + 8.f)){
      float mn = fmaxf(m_run, tmax);
      float corr = __expf(m_run - mn);
      m_run = mn;
      l_run *= corr;
      #pragma unroll
      for (int reg=0; reg<16; reg++){
        int qn = (reg&3) + 8*(reg>>2) + 4*hi;   // acc row -> q
        float ca = __shfl(corr, qn);            // lanes 0..31 hold q=l31 state
        acc0[reg] *= ca; acc1[reg] *= ca;
      }
    }

    // ---- exp + row sum
    float rs = 0.f;
    #pragma unroll
    for (int i=0;i<16;i++){
      sc0[i] = __expf(sc0[i]-m_run); rs += sc0[i];
      sc1[i] = __expf(sc1[i]-m_run); rs += sc1[i];
    }
    rs += __shfl_xor(rs, 32);
    l_run += rs;

    // ---- pack P to bf16 pairs: pk[kt'][rg][w] = (c=2w, c=2w+1)
    unsigned pk0[8], pk1[8];
    #pragma unroll
    for (int rg=0; rg<4; rg++){
      pk0[rg*2+0] = cvtpk(sc0[rg*4+0], sc0[rg*4+1]);
      pk0[rg*2+1] = cvtpk(sc0[rg*4+2], sc0[rg*4+3]);
      pk1[rg*2+0] = cvtpk(sc1[rg*4+0], sc1[rg*4+1]);
      pk1[rg*2+1] = cvtpk(sc1[rg*4+2], sc1[rg*4+3]);
    }

    // ---- build A-frags (k = kt*16 + 8*hi + j) via half-exchange + PV
    __builtin_amdgcn_s_setprio(1);
    #pragma unroll
    for (int kt=0; kt<4; kt++){
      const unsigned* pk = (kt<2)? pk0 : pk1;
      const int tA = 2*(kt&1);
      unsigned X0 = pk[tA*2+0], X1 = pk[tA*2+1];
      unsigned Y0 = pk[tA*2+2], Y1 = pk[tA*2+3];
      unsigned X0s = __shfl_xor(X0,32), X1s = __shfl_xor(X1,32);
      unsigned Y0s = __shfl_xor(Y0,32), Y1s = __shfl_xor(Y1,32);
      union { unsigned u[4]; bf16x8 v; } pu;
      pu.u[0] = hi ? Y0s : X0;
      pu.u[1] = hi ? Y1s : X1;
      pu.u[2] = hi ? Y0  : X0s;
      pu.u[3] = hi ? Y1  : X1s;
      bf16x8 v0 = *(const bf16x8*)&Vs[SWZ64(wc*64 +      l31, kt*16 + hi*8)];
      bf16x8 v1 = *(const bf16x8*)&Vs[SWZ64(wc*64 + 32 + l31, kt*16 + hi*8)];
      acc0 = MFMA32(pu.v, v0, acc0);
      acc1 = MFMA32(pu.v, v1, acc1);
    }
    __builtin_amdgcn_s_setprio(0);
  }

  // ---- epilogue: normalize by l (redistributed to acc layout), store
  const size_t rowbase = (size_t)split*16384 + (size_t)b*4096 + q0;
  #pragma unroll
  for (int reg=0; reg<16; reg++){
    int qn = (reg&3) + 8*(reg>>2) + 4*hi;
    float lv = __shfl(l_run, qn);
    float inv = 1.f/lv;
    size_t row = rowbase + wr*32 + qn;
    opart[row*128 + wc*64 +      l31] = f2bf(acc0[reg]*inv);
    opart[row*128 + wc*64 + 32 + l31] = f2bf(acc1[reg]*inv);
  }
  if (hi==0){
    size_t rg = rowbase + wr*32 + l31;
    ml[rg*2]   = m_run;
    ml[rg*2+1] = l_run;
  }
}

// ---------------------------------------------------------------------------
// Kernel 3: merge 4 KV-split partials + out-projection.
// ---------------------------------------------------------------------------
__global__ __launch_bounds__(256) void k_outproj(
    const unsigned short* __restrict__ opart, const float* __restrict__ ml,
    const float* __restrict__ p_w, const float* __restrict__ p_b,
    float* __restrict__ out)
{
  const int tid = threadIdx.x;
  const int row0 = blockIdx.x*64;   // global row in [0,16384)
  __shared__ __align__(16) unsigned short Wt[128][136];
  __shared__ __align__(16) unsigned short Xs[64][136];
  __shared__ float wmg[4][64];

  #pragma unroll 4
  for (int i=0;i<16;i++){
    int idx = tid*64 + i*4;
    float4 v4 = *(const float4*)(p_w + idx);
    Wt[(idx+0)&127][(idx+0)>>7] = f2bf(v4.x);
    Wt[(idx+1)&127][(idx+1)>>7] = f2bf(v4.y);
    Wt[(idx+2)&127][(idx+2)>>7] = f2bf(v4.z);
    Wt[(idx+3)&127][(idx+3)>>7] = f2bf(v4.w);
  }
  if (tid < 64){
    int row = row0 + tid;
    float m[4], l[4];
    #pragma unroll
    for (int i=0;i<4;i++){
      m[i] = ml[((size_t)i*16384 + row)*2];
      l[i] = ml[((size_t)i*16384 + row)*2 + 1];
    }
    float M = fmaxf(fmaxf(m[0],m[1]),fmaxf(m[2],m[3]));
    float wi[4], wsum = 0.f;
    #pragma unroll
    for (int i=0;i<4;i++){ wi[i] = __expf(m[i]-M)*l[i]; wsum += wi[i]; }
    float inv = 1.f/wsum;
    #pragma unroll
    for (int i=0;i<4;i++) wmg[i][tid] = wi[i]*inv;
  }
  __syncthreads();
  #pragma unroll
  for (int i=0;i<4;i++){
    int e = tid*32 + i*8;
    int row = e>>7, col = e&127;
    float a8[8];
    #pragma unroll
    for (int j=0;j<8;j++) a8[j] = 0.f;
    #pragma unroll
    for (int s=0;s<4;s++){
      uint4 v = *(const uint4*)(opart + ((size_t)s*16384 + row0 + row)*128 + col);
      float wv = wmg[s][row];
      const unsigned short* hp = (const unsigned short*)&v;
      #pragma unroll
      for (int j=0;j<8;j++) a8[j] += wv * bf2f(hp[j]);
    }
    unsigned short h8[8];
    #pragma unroll
    for (int j=0;j<8;j++) h8[j] = f2bf(a8[j]);
    *(uint4*)&Xs[row][col] = *(const uint4*)h8;
  }
  __syncthreads();

  const int w=tid>>6, lane=tid&63, lr=lane&15, lg=lane>>4;
  f32x4 acc[8];
  #pragma unroll
  for (int nt=0;nt<8;nt++) acc[nt] = (f32x4){0.f,0.f,0.f,0.f};
  #pragma unroll
  for (int kk=0;kk<4;kk++){
    bf16x8 a = *(const bf16x8*)&Xs[w*16+lr][kk*32+lg*8];
    #pragma unroll
    for (int nt=0;nt<8;nt++){
      bf16x8 bb = *(const bf16x8*)&Wt[nt*16+lr][kk*32+lg*8];
      acc[nt] = MFMA16(a,bb,acc[nt]);
    }
  }
  #pragma unroll
  for (int nt=0;nt<8;nt++){
    int col = nt*16+lr;
    float pb = p_b[col];
    #pragma unroll
    for (int r=0;r<4;r++){
      int row = row0 + w*16 + lg*4 + r;
      out[(size_t)row*128+col] = acc[nt][r] + pb;
    }
  }
}

extern "C" void kernel_launch(void* const* d_in, const int* in_sizes, int n_in,
                              void* d_out, int out_size, void* d_ws, size_t ws_size,
                              hipStream_t stream) {
  (void)in_sizes; (void)n_in; (void)out_size; (void)ws_size;
  const float* query    = (const float*)d_in[0];
  const float* key      = (const float*)d_in[1];
  const float* value    = (const float*)d_in[2];
  const float* att_bias = (const float*)d_in[3];
  const float* q_w = (const float*)d_in[4];
  const float* q_b = (const float*)d_in[5];
  const float* k_w = (const float*)d_in[6];
  const float* v_w = (const float*)d_in[7];
  const float* v_b = (const float*)d_in[8];
  const float* vs_w = (const float*)d_in[9];
  const float* vs_b = (const float*)d_in[10];
  const float* p_w = (const float*)d_in[11];
  const float* p_b = (const float*)d_in[12];

  char* ws = (char*)d_ws;
  unsigned short* qp    = (unsigned short*)(ws);             // 4 MB
  unsigned short* kp    = (unsigned short*)(ws + 4194304);   // 4 MB
  unsigned short* vpt   = (unsigned short*)(ws + 8388608);   // 4 MB  [b][d][n]
  float*          biasc = (float*)(ws + 12582912);           // 64 KB
  unsigned short* opart = (unsigned short*)(ws + 12648448);  // 16 MB [split][b][q][d]
  float*          ml    = (float*)(ws + 29425664);           // 512 KB

  hipLaunchKernelGGL(k_proj, dim3(256,3), dim3(256), 0, stream,
    query,key,value,att_bias,q_w,q_b,k_w,v_w,v_b,vs_w,vs_b,qp,kp,vpt,biasc);
  hipLaunchKernelGGL(k_flash, dim3(64,4,4), dim3(256), 0, stream,
    qp,kp,vpt,biasc,opart,ml);
  hipLaunchKernelGGL(k_outproj, dim3(256), dim3(256), 0, stream,
    opart,ml,p_w,p_b,(float*)d_out);
}